// Round 1
// baseline (16402.121 us; speedup 1.0000x reference)
//
#include <hip/hip_runtime.h>
#include <math.h>

#define T_STEPS 512
#define B_SZ    128
#define I_SZ    256
#define H_SZ    512
#define HX_SZ   768
#define NG      2048      // 4*H gate-columns, packed n = jh*4 + gate
#define KB_H    16        // k-instructions covering h part (512/32)
#define KB_X    8         // k-instructions covering x part (256/32)
#define KB_TOT  24        // total k-instructions (768/32)
#define W_ELEMS (HX_SZ * NG)   // 1,572,864 per pack
#define NWG     256

typedef __attribute__((ext_vector_type(8))) short bf16x8;   // MFMA A/B frag (4 VGPRs)
typedef __attribute__((ext_vector_type(4))) short bf16x4;   // 8B LDS store
typedef __attribute__((ext_vector_type(4))) float f32x4;    // MFMA C/D frag

__device__ __forceinline__ unsigned short f2bf_rne(float f) {
    unsigned u = __builtin_bit_cast(unsigned, f);
    unsigned r = u + 0x7fffu + ((u >> 16) & 1u);
    return (unsigned short)(r >> 16);
}
__device__ __forceinline__ float bf2f(unsigned short h) {
    unsigned u = ((unsigned)h) << 16;
    return __builtin_bit_cast(float, u);
}

// ---- Pack W{f,i,c,o}[768][512] into MFMA-B-fragment order, bf16 hi + lo ----
// dst flat index: id = ((ng*KB_TOT + kb)*64 + lane)*8 + j
//   n = ng*16 + (lane&15); k = kb*32 + (lane>>4)*8 + j;  element = W[k][n]
__global__ __launch_bounds__(256) void repack_frag(
    const float* __restrict__ Wf, const float* __restrict__ Wi,
    const float* __restrict__ Wc, const float* __restrict__ Wo,
    unsigned short* __restrict__ Whi, unsigned short* __restrict__ Wlo)
{
    int id = blockIdx.x * 256 + threadIdx.x;           // [0, 1572864)
    int j    = id & 7;
    int lane = (id >> 3) & 63;
    int fkb  = (id >> 9);
    int kb   = fkb % KB_TOT;
    int ng   = fkb / KB_TOT;
    int n = ng * 16 + (lane & 15);
    int k = kb * 32 + (lane >> 4) * 8 + j;
    int g  = n & 3;
    int jh = n >> 2;
    const float* Ws = (g == 0) ? Wf : (g == 1) ? Wi : (g == 2) ? Wc : Wo;
    float w = Ws[k * H_SZ + jh];
    unsigned short wh = f2bf_rne(w);
    unsigned short wl = f2bf_rne(w - bf2f(wh));
    Whi[id] = wh;
    Wlo[id] = wl;
}

__global__ __launch_bounds__(256) void pack_bias(
    const float* __restrict__ bf, const float* __restrict__ bi,
    const float* __restrict__ bc, const float* __restrict__ bo,
    float* __restrict__ bpk, unsigned int* __restrict__ tok)
{
    int c = blockIdx.x * 256 + threadIdx.x;   // [0, 2048)
    if (c < NWG) tok[(size_t)c * 16] = 0u;    // zero barrier tokens each replay
    int jh = c >> 2, g = c & 3;
    const float* bs = (g == 0) ? bf : (g == 1) ? bi : (g == 2) ? bc : bo;
    bpk[c] = bs[jh];
}

// ---- Persistent LSTM: all 512 timesteps in one launch ----
// 256 WGs x 256 thr, 1 WG/CU. WG w: xcd=w&7, q=w>>3, bt=q&7 (16-row b-tile),
// ngg=xcd*4+(q>>3) in [0,32) (64 gate-cols). Wave wv: ng=ngg*4+wv (16 cols).
// Weights (hi+lo frags, full K) live in 192 VGPRs per wave for the whole kernel.
// 8 independent sync groups (one per b-tile): 32-WG token barrier per step.
__global__ __launch_bounds__(256, 1) void lstm_persist(
    const float* __restrict__ x_all,           // [T][B][I] fp32
    const unsigned short* __restrict__ Whi,    // frag-packed bf16 hi
    const unsigned short* __restrict__ Wlo,    // frag-packed bf16 lo
    const float* __restrict__ bpk,             // [2048] packed bias
    float* __restrict__ out,                   // [T][B][H] fp32
    unsigned short* __restrict__ hhi,          // [2][B][H] bf16 hi (double buf)
    unsigned short* __restrict__ hlo,          // [2][B][H] bf16 lo
    unsigned int* __restrict__ tok)            // [NWG*16] barrier tokens
{
    __shared__ __align__(16) unsigned short sh_hi[16 * 512];
    __shared__ __align__(16) unsigned short sh_lo[16 * 512];
    __shared__ __align__(16) unsigned short sx_hi[16 * 256];
    __shared__ __align__(16) unsigned short sx_lo[16 * 256];
    __shared__ float preact[16][64];

    const int tid  = threadIdx.x;
    const int lane = tid & 63;
    const int wv   = tid >> 6;
    const int w    = blockIdx.x;
    const int xcd  = w & 7;
    const int q    = w >> 3;
    const int bt   = q & 7;
    const int ngg  = xcd * 4 + (q >> 3);
    const int ng   = ngg * 4 + wv;
    const int b0   = bt * 16;
    const int mrow = lane & 15;
    const int quad = lane >> 4;
    const int grpbase = bt * 32;            // this group's 32 token slots
    const int myslot  = grpbase + ngg;

    // ---- load weight fragments into registers (once) ----
    bf16x8 wh[KB_TOT], wl[KB_TOT];
    {
        const bf16x8* __restrict__ Wh8 = (const bf16x8*)Whi;
        const bf16x8* __restrict__ Wl8 = (const bf16x8*)Wlo;
        const int wbase = ng * KB_TOT * 64 + lane;
        #pragma unroll
        for (int kb = 0; kb < KB_TOT; ++kb) {
            wh[kb] = Wh8[wbase + kb * 64];
            wl[kb] = Wl8[wbase + kb * 64];
        }
    }

    // ---- pointwise role: thread -> (b_local, hidden_local); C stays in reg ----
    const int bl = tid >> 4;
    const int jl = tid & 15;
    const int pidx = (b0 + bl) * H_SZ + ngg * 16 + jl;
    const f32x4 bias = ((const f32x4*)bpk)[ngg * 16 + jl];
    float Creg = 0.f;

    // ---- staging offsets (short units); XOR swizzle = ((row&7)<<3) shorts ----
    int hgo[4], xgo[4], hlds[4], xlds[4];
    #pragma unroll
    for (int r = 0; r < 4; ++r) {
        const int row = r * 4 + wv;
        hgo[r]  = (b0 + row) * H_SZ + lane * 8;                      // 16B chunk
        hlds[r] = (row * 512 + lane * 8) ^ ((row & 7) << 3);
        xgo[r]  = (b0 + row) * I_SZ + lane * 4;                      // 4 floats
        xlds[r] = (row * 256 + lane * 4) ^ ((row & 7) << 3);
    }
    const int hfr = mrow * 512 + quad * 8;   // A-frag read base (shorts)
    const int xfr = mrow * 256 + quad * 8;
    const int swz = (mrow & 7) << 3;

    for (int t = 0; t < T_STEPS; ++t) {
        const float* __restrict__ xt = x_all + (size_t)t * (B_SZ * I_SZ);

        // ---- stage x(t): fp32 -> bf16 hi/lo into LDS (once per WG) ----
        #pragma unroll
        for (int r = 0; r < 4; ++r) {
            const f32x4 xv = *(const f32x4*)(xt + xgo[r]);
            bf16x4 hv, lv;
            #pragma unroll
            for (int j = 0; j < 4; ++j) {
                const unsigned short hb = f2bf_rne(xv[j]);
                hv[j] = (short)hb;
                lv[j] = (short)f2bf_rne(xv[j] - bf2f(hb));
            }
            *(bf16x4*)&sx_hi[xlds[r]] = hv;
            *(bf16x4*)&sx_lo[xlds[r]] = lv;
        }
        __syncthreads();

        // ---- x-part MFMAs (independent of h(t-1): runs under barrier latency)
        f32x4 acc = {0.f, 0.f, 0.f, 0.f};
        #pragma unroll
        for (int kxb = 0; kxb < KB_X; ++kxb) {
            const int off = (xfr + kxb * 32) ^ swz;
            const bf16x8 xh = *(const bf16x8*)&sx_hi[off];
            const bf16x8 xl = *(const bf16x8*)&sx_lo[off];
            acc = __builtin_amdgcn_mfma_f32_16x16x32_bf16(xh, wh[KB_H + kxb], acc, 0, 0, 0);
            acc = __builtin_amdgcn_mfma_f32_16x16x32_bf16(xl, wh[KB_H + kxb], acc, 0, 0, 0);
            acc = __builtin_amdgcn_mfma_f32_16x16x32_bf16(xh, wl[KB_H + kxb], acc, 0, 0, 0);
        }

        if (t > 0) {
            // ---- wait for this group's h(t-1): 32 tokens >= t ----
            if (tid < 32) {
                const unsigned int* tp = tok + (size_t)(grpbase + tid) * 16;
                while (__hip_atomic_load(tp, __ATOMIC_RELAXED,
                                         __HIP_MEMORY_SCOPE_AGENT) < (unsigned)t)
                    __builtin_amdgcn_s_sleep(1);
            }
            __syncthreads();
            __threadfence();   // acquire: invalidate stale L1/L2 before h loads

            // ---- stage h(t-1) hi/lo into LDS (swizzled) ----
            const unsigned short* __restrict__ hh = hhi + ((t - 1) & 1) * (B_SZ * H_SZ);
            const unsigned short* __restrict__ hl = hlo + ((t - 1) & 1) * (B_SZ * H_SZ);
            #pragma unroll
            for (int r = 0; r < 4; ++r) {
                const bf16x8 vh = *(const bf16x8*)(hh + hgo[r]);
                const bf16x8 vl = *(const bf16x8*)(hl + hgo[r]);
                *(bf16x8*)&sh_hi[hlds[r]] = vh;
                *(bf16x8*)&sh_lo[hlds[r]] = vl;
            }
            __syncthreads();

            // ---- h-part MFMAs ----
            #pragma unroll
            for (int kb = 0; kb < KB_H; ++kb) {
                const int off = (hfr + kb * 32) ^ swz;
                const bf16x8 ah = *(const bf16x8*)&sh_hi[off];
                const bf16x8 al = *(const bf16x8*)&sh_lo[off];
                acc = __builtin_amdgcn_mfma_f32_16x16x32_bf16(ah, wh[kb], acc, 0, 0, 0);
                acc = __builtin_amdgcn_mfma_f32_16x16x32_bf16(al, wh[kb], acc, 0, 0, 0);
                acc = __builtin_amdgcn_mfma_f32_16x16x32_bf16(ah, wl[kb], acc, 0, 0, 0);
            }
        }

        // ---- stage pre-activations (D: col=lane&15, row=quad*4+r) ----
        #pragma unroll
        for (int r = 0; r < 4; ++r)
            preact[quad * 4 + r][wv * 16 + mrow] = acc[r];
        __syncthreads();

        // ---- pointwise ----
        const float pf = preact[bl][jl * 4 + 0] + bias[0];
        const float pi = preact[bl][jl * 4 + 1] + bias[1];
        const float pc = preact[bl][jl * 4 + 2] + bias[2];
        const float po = preact[bl][jl * 4 + 3] + bias[3];
        const float fg = 1.f / (1.f + __expf(-pf));
        const float ig = 1.f / (1.f + __expf(-pi));
        const float cb = tanhf(pc);
        const float og = 1.f / (1.f + __expf(-po));
        const float Cn = fg * Creg + ig * cb;
        const float hn = og * tanhf(Cn);
        Creg = Cn;

        const int pw = t & 1;
        const unsigned short hb16 = f2bf_rne(hn);
        hhi[pw * (B_SZ * H_SZ) + pidx] = hb16;
        hlo[pw * (B_SZ * H_SZ) + pidx] = f2bf_rne(hn - bf2f(hb16));
        __syncthreads();   // drains every wave's vmcnt -> all WG h-stores done
        if (tid == 0) {
            __threadfence();  // release: flush to agent coherence point
            __hip_atomic_store(tok + (size_t)myslot * 16, (unsigned)(t + 1),
                               __ATOMIC_RELAXED, __HIP_MEMORY_SCOPE_AGENT);
        }
        out[(size_t)t * (B_SZ * H_SZ) + pidx] = hn;   // not barrier-protected
    }
}

extern "C" void kernel_launch(void* const* d_in, const int* in_sizes, int n_in,
                              void* d_out, int out_size, void* d_ws, size_t ws_size,
                              hipStream_t stream)
{
    const float* x  = (const float*)d_in[0];
    const float* Wf = (const float*)d_in[1];
    const float* bf = (const float*)d_in[2];
    const float* Wi = (const float*)d_in[3];
    const float* bi = (const float*)d_in[4];
    const float* Wc = (const float*)d_in[5];
    const float* bc = (const float*)d_in[6];
    const float* Wo = (const float*)d_in[7];
    const float* bo = (const float*)d_in[8];
    float* out = (float*)d_out;

    // ---- workspace layout (all 16B aligned) ----
    unsigned short* Whi = (unsigned short*)d_ws;          // 1,572,864 shorts
    unsigned short* Wlo = Whi + W_ELEMS;                  // 1,572,864 shorts
    float* bpk = (float*)(Wlo + W_ELEMS);                 // 2048 floats
    unsigned short* hb = (unsigned short*)(bpk + NG);
    unsigned short* hhi = hb;                             // [2][65536]
    unsigned short* hlo = hb + 2 * (B_SZ * H_SZ);         // [2][65536]
    unsigned int* tok = (unsigned int*)(hlo + 2 * (B_SZ * H_SZ)); // 256*16 uints

    repack_frag<<<W_ELEMS / 256, 256, 0, stream>>>(Wf, Wi, Wc, Wo, Whi, Wlo);
    pack_bias<<<NG / 256, 256, 0, stream>>>(bf, bi, bc, bo, bpk, tok);
    lstm_persist<<<NWG, 256, 0, stream>>>(x, Whi, Wlo, bpk, out, hhi, hlo, tok);
}

// Round 2
// 2440.995 us; speedup vs baseline: 6.7194x; 6.7194x over previous
//
#include <hip/hip_runtime.h>
#include <math.h>

#define T_STEPS 512
#define B_SZ    128
#define I_SZ    256
#define H_SZ    512
#define HX_SZ   768
#define NG      2048      // 4*H gate-columns, packed n = jh*4 + gate
#define KB_H    16        // k-instructions covering h part (512/32)
#define KB_X    8         // k-instructions covering x part (256/32)
#define KB_TOT  24        // total k-instructions (768/32)
#define W_ELEMS (HX_SZ * NG)   // 1,572,864 per pack
#define NWG     256
#define BH      (B_SZ * H_SZ)

typedef __attribute__((ext_vector_type(8))) short bf16x8;   // MFMA A/B frag (4 VGPRs)
typedef __attribute__((ext_vector_type(4))) short bf16x4;   // 8B LDS store
typedef __attribute__((ext_vector_type(4))) float f32x4;    // MFMA C/D frag

__device__ __forceinline__ unsigned short f2bf_rne(float f) {
    unsigned u = __builtin_bit_cast(unsigned, f);
    unsigned r = u + 0x7fffu + ((u >> 16) & 1u);
    return (unsigned short)(r >> 16);
}
__device__ __forceinline__ float bf2f(unsigned short h) {
    unsigned u = ((unsigned)h) << 16;
    return __builtin_bit_cast(float, u);
}

// ---- Pack W{f,i,c,o}[768][512] into MFMA-B-fragment order, bf16 hi + lo ----
// dst flat index: id = ((ng*KB_TOT + kb)*64 + lane)*8 + j
//   n = ng*16 + (lane&15); k = kb*32 + (lane>>4)*8 + j;  element = W[k][n]
__global__ __launch_bounds__(256) void repack_frag(
    const float* __restrict__ Wf, const float* __restrict__ Wi,
    const float* __restrict__ Wc, const float* __restrict__ Wo,
    unsigned short* __restrict__ Whi, unsigned short* __restrict__ Wlo)
{
    int id = blockIdx.x * 256 + threadIdx.x;           // [0, 1572864)
    int j    = id & 7;
    int lane = (id >> 3) & 63;
    int fkb  = (id >> 9);
    int kb   = fkb % KB_TOT;
    int ng   = fkb / KB_TOT;
    int n = ng * 16 + (lane & 15);
    int k = kb * 32 + (lane >> 4) * 8 + j;
    int g  = n & 3;
    int jh = n >> 2;
    const float* Ws = (g == 0) ? Wf : (g == 1) ? Wi : (g == 2) ? Wc : Wo;
    float w = Ws[k * H_SZ + jh];
    unsigned short wh = f2bf_rne(w);
    unsigned short wl = f2bf_rne(w - bf2f(wh));
    Whi[id] = wh;
    Wlo[id] = wl;
}

__global__ __launch_bounds__(256) void pack_bias(
    const float* __restrict__ bf, const float* __restrict__ bi,
    const float* __restrict__ bc, const float* __restrict__ bo,
    float* __restrict__ bpk, unsigned int* __restrict__ tok)
{
    int c = blockIdx.x * 256 + threadIdx.x;   // [0, 2048)
    if (c < NWG) tok[(size_t)c * 16] = 0u;    // zero group counters each replay
    int jh = c >> 2, g = c & 3;
    const float* bs = (g == 0) ? bf : (g == 1) ? bi : (g == 2) ? bc : bo;
    bpk[c] = bs[jh];
}

// ---- Persistent LSTM: all 512 timesteps in one launch ----
// 256 WGs x 256 thr, 1 WG/CU (deadlock-free: grid == CU count at any VGPR use).
// WG w: xcd=w&7, q=w>>3, bt=q&7 (16-row b-tile), ngg=xcd*4+(q>>3) in [0,32).
// Wave wv: ng=ngg*4+wv (16 gate cols, full K). Weights (hi+lo frags) pinned in
// 192 VGPRs/wave via asm keep-alive. 8 independent sync groups (one per b-tile):
// h exchanged through the device coherence point with sc0 sc1 loads/stores
// (no stale cached copies possible -> NO fences, NO cache invalidation),
// one relaxed agent atomic counter per group (32 adds/step, poll >= 32*t).
__global__ __launch_bounds__(256, 1) void lstm_persist(
    const float* __restrict__ x_all,           // [T][B][I] fp32
    const unsigned short* __restrict__ Whi,    // frag-packed bf16 hi
    const unsigned short* __restrict__ Wlo,    // frag-packed bf16 lo
    const float* __restrict__ bpk,             // [2048] packed bias
    float* __restrict__ out,                   // [T][B][H] fp32
    unsigned short* __restrict__ hhi,          // [2][B][H] bf16 hi (double buf)
    unsigned short* __restrict__ hlo,          // [2][B][H] bf16 lo
    unsigned int* __restrict__ tok)            // group counters at tok[bt*16]
{
    __shared__ __align__(16) unsigned short sh_hi[16 * 512];
    __shared__ __align__(16) unsigned short sh_lo[16 * 512];
    __shared__ __align__(16) unsigned short sx_hi[16 * 256];
    __shared__ __align__(16) unsigned short sx_lo[16 * 256];
    __shared__ float preact[16][64];

    const int tid  = threadIdx.x;
    const int lane = tid & 63;
    const int wv   = tid >> 6;
    const int w    = blockIdx.x;
    const int xcd  = w & 7;
    const int q    = w >> 3;
    const int bt   = q & 7;
    const int ngg  = xcd * 4 + (q >> 3);
    const int ng   = ngg * 4 + wv;
    const int b0   = bt * 16;
    const int mrow = lane & 15;
    const int quad = lane >> 4;
    unsigned int* const gcnt = tok + (size_t)bt * 16;

    // ---- load weight fragments once; pin in VGPRs (anti-remat keep-alive) ----
    bf16x8 wh[KB_TOT], wl[KB_TOT];
    {
        const bf16x8* __restrict__ Wh8 = (const bf16x8*)Whi;
        const bf16x8* __restrict__ Wl8 = (const bf16x8*)Wlo;
        const int wbase = ng * KB_TOT * 64 + lane;
        #pragma unroll
        for (int kb = 0; kb < KB_TOT; ++kb) {
            wh[kb] = Wh8[wbase + kb * 64];
            wl[kb] = Wl8[wbase + kb * 64];
        }
    }
    #pragma unroll
    for (int kb = 0; kb < KB_TOT; ++kb) {
        asm volatile("" : "+v"(wh[kb]));
        asm volatile("" : "+v"(wl[kb]));
    }

    // ---- pointwise role: thread -> (b_local, hidden_local); C stays in reg ----
    const int bl = tid >> 4;
    const int jl = tid & 15;
    const int pidx = (b0 + bl) * H_SZ + ngg * 16 + jl;
    const f32x4 bias = ((const f32x4*)bpk)[ngg * 16 + jl];
    float Creg = 0.f;

    // ---- staging offsets (short units); XOR swizzle = ((row&7)<<3) shorts ----
    int hgo[4], xgo[4], hlds[4], xlds[4];
    #pragma unroll
    for (int r = 0; r < 4; ++r) {
        const int row = r * 4 + wv;
        hgo[r]  = (b0 + row) * H_SZ + lane * 8;                      // 16B chunk
        hlds[r] = (row * 512 + lane * 8) ^ ((row & 7) << 3);
        xgo[r]  = (b0 + row) * I_SZ + lane * 4;                      // 4 floats
        xlds[r] = (row * 256 + lane * 4) ^ ((row & 7) << 3);
    }
    const int hfr = mrow * 512 + quad * 8;   // A-frag read base (shorts)
    const int xfr = mrow * 256 + quad * 8;
    const int swz = (mrow & 7) << 3;

    for (int t = 0; t < T_STEPS; ++t) {
        const float* __restrict__ xt = x_all + (size_t)t * (B_SZ * I_SZ);

        // ---- stage x(t): fp32 -> bf16 hi/lo into LDS (once per WG) ----
        #pragma unroll
        for (int r = 0; r < 4; ++r) {
            const f32x4 xv = *(const f32x4*)(xt + xgo[r]);
            bf16x4 hv, lv;
            #pragma unroll
            for (int j = 0; j < 4; ++j) {
                const unsigned short hb = f2bf_rne(xv[j]);
                hv[j] = (short)hb;
                lv[j] = (short)f2bf_rne(xv[j] - bf2f(hb));
            }
            *(bf16x4*)&sx_hi[xlds[r]] = hv;
            *(bf16x4*)&sx_lo[xlds[r]] = lv;
        }
        __syncthreads();   // B1: sx ready

        // ---- x-part MFMAs (independent of h(t-1): overlaps group latency) ----
        f32x4 acc = {0.f, 0.f, 0.f, 0.f};
        #pragma unroll
        for (int kxb = 0; kxb < KB_X; ++kxb) {
            const int off = (xfr + kxb * 32) ^ swz;
            const bf16x8 xh = *(const bf16x8*)&sx_hi[off];
            const bf16x8 xl = *(const bf16x8*)&sx_lo[off];
            acc = __builtin_amdgcn_mfma_f32_16x16x32_bf16(xh, wh[KB_H + kxb], acc, 0, 0, 0);
            acc = __builtin_amdgcn_mfma_f32_16x16x32_bf16(xl, wh[KB_H + kxb], acc, 0, 0, 0);
            acc = __builtin_amdgcn_mfma_f32_16x16x32_bf16(xh, wl[KB_H + kxb], acc, 0, 0, 0);
        }

        if (t > 0) {
            // ---- wait for this group's 32 step-(t-1) producers ----
            if (tid == 0) {
                const unsigned target = 32u * (unsigned)t;
                while (__hip_atomic_load(gcnt, __ATOMIC_RELAXED,
                                         __HIP_MEMORY_SCOPE_AGENT) < target)
                    __builtin_amdgcn_s_sleep(2);
            }
            __syncthreads();   // B2: h(t-1) visible at coherence point

            // ---- load h(t-1) hi/lo via device-coherent sc0 sc1 (bypass L1/L2) ----
            const unsigned short* __restrict__ hh = hhi + ((t - 1) & 1) * BH;
            const unsigned short* __restrict__ hl = hlo + ((t - 1) & 1) * BH;
            bf16x8 vh[4], vl[4];
            #pragma unroll
            for (int r = 0; r < 4; ++r) {
                asm volatile("global_load_dwordx4 %0, %1, off sc0 sc1"
                             : "=v"(vh[r]) : "v"(hh + hgo[r]));
                asm volatile("global_load_dwordx4 %0, %1, off sc0 sc1"
                             : "=v"(vl[r]) : "v"(hl + hgo[r]));
            }
            asm volatile("s_waitcnt vmcnt(0)" ::: "memory");
            __builtin_amdgcn_sched_barrier(0);
            #pragma unroll
            for (int r = 0; r < 4; ++r) {
                *(bf16x8*)&sh_hi[hlds[r]] = vh[r];
                *(bf16x8*)&sh_lo[hlds[r]] = vl[r];
            }
            __syncthreads();   // B3: sh ready

            // ---- h-part MFMAs ----
            #pragma unroll
            for (int kb = 0; kb < KB_H; ++kb) {
                const int off = (hfr + kb * 32) ^ swz;
                const bf16x8 ah = *(const bf16x8*)&sh_hi[off];
                const bf16x8 al = *(const bf16x8*)&sh_lo[off];
                acc = __builtin_amdgcn_mfma_f32_16x16x32_bf16(ah, wh[kb], acc, 0, 0, 0);
                acc = __builtin_amdgcn_mfma_f32_16x16x32_bf16(al, wh[kb], acc, 0, 0, 0);
                acc = __builtin_amdgcn_mfma_f32_16x16x32_bf16(ah, wl[kb], acc, 0, 0, 0);
            }
        }

        // ---- stage pre-activations (D: col=lane&15, row=quad*4+r) ----
        #pragma unroll
        for (int r = 0; r < 4; ++r)
            preact[quad * 4 + r][wv * 16 + mrow] = acc[r];
        __syncthreads();   // B4: preact ready

        // ---- pointwise ----
        const float pf = preact[bl][jl * 4 + 0] + bias[0];
        const float pi = preact[bl][jl * 4 + 1] + bias[1];
        const float pc = preact[bl][jl * 4 + 2] + bias[2];
        const float po = preact[bl][jl * 4 + 3] + bias[3];
        const float fg = 1.f / (1.f + __expf(-pf));
        const float ig = 1.f / (1.f + __expf(-pi));
        const float cb = tanhf(pc);
        const float og = 1.f / (1.f + __expf(-po));
        const float Cn = fg * Creg + ig * cb;
        const float hn = og * tanhf(Cn);
        Creg = Cn;

        const int pw = t & 1;
        const unsigned short hb16 = f2bf_rne(hn);
        const unsigned short lb16 = f2bf_rne(hn - bf2f(hb16));
        {   // h stores through the coherence point (sc0 sc1): no fence needed
            const unsigned short* ph = hhi + pw * BH + pidx;
            const unsigned short* pl = hlo + pw * BH + pidx;
            const unsigned int hv = hb16, lv = lb16;
            asm volatile("global_store_short %0, %1, off sc0 sc1"
                         :: "v"(ph), "v"(hv) : "memory");
            asm volatile("global_store_short %0, %1, off sc0 sc1"
                         :: "v"(pl), "v"(lv) : "memory");
        }
        out[(size_t)t * BH + pidx] = hn;   // plain store, kernel-end visible

        __syncthreads();   // B5: emits s_waitcnt vmcnt(0) -> all WG h-stores at MALL
        if (tid == 0)
            __hip_atomic_fetch_add(gcnt, 1u, __ATOMIC_RELAXED,
                                   __HIP_MEMORY_SCOPE_AGENT);
    }
}

extern "C" void kernel_launch(void* const* d_in, const int* in_sizes, int n_in,
                              void* d_out, int out_size, void* d_ws, size_t ws_size,
                              hipStream_t stream)
{
    const float* x  = (const float*)d_in[0];
    const float* Wf = (const float*)d_in[1];
    const float* bf = (const float*)d_in[2];
    const float* Wi = (const float*)d_in[3];
    const float* bi = (const float*)d_in[4];
    const float* Wc = (const float*)d_in[5];
    const float* bc = (const float*)d_in[6];
    const float* Wo = (const float*)d_in[7];
    const float* bo = (const float*)d_in[8];
    float* out = (float*)d_out;

    // ---- workspace layout (all 16B aligned) ----
    unsigned short* Whi = (unsigned short*)d_ws;          // 1,572,864 shorts
    unsigned short* Wlo = Whi + W_ELEMS;                  // 1,572,864 shorts
    float* bpk = (float*)(Wlo + W_ELEMS);                 // 2048 floats
    unsigned short* hb = (unsigned short*)(bpk + NG);
    unsigned short* hhi = hb;                             // [2][65536]
    unsigned short* hlo = hb + 2 * BH;                    // [2][65536]
    unsigned int* tok = (unsigned int*)(hlo + 2 * BH);    // 256*16 uints

    repack_frag<<<W_ELEMS / 256, 256, 0, stream>>>(Wf, Wi, Wc, Wo, Whi, Wlo);
    pack_bias<<<NG / 256, 256, 0, stream>>>(bf, bi, bc, bo, bpk, tok);
    lstm_persist<<<NWG, 256, 0, stream>>>(x, Whi, Wlo, bpk, out, hhi, hlo, tok);
}

// Round 4
// 1855.562 us; speedup vs baseline: 8.8394x; 1.3155x over previous
//
#include <hip/hip_runtime.h>
#include <math.h>

#define T_STEPS 512
#define B_SZ    128
#define I_SZ    256
#define H_SZ    512
#define HX_SZ   768
#define NG      2048      // 4*H gate-columns, packed n = jh*4 + gate
#define KB_H    16        // k-instructions covering h part (512/32)
#define KB_X    8         // k-instructions covering x part (256/32)
#define KB_TOT  24        // total k-instructions (768/32)
#define W_ELEMS (HX_SZ * NG)   // 1,572,864 per pack
#define NWG     256
#define BH      (B_SZ * H_SZ)
#define BI      (B_SZ * I_SZ)
#define NFLAG   128       // per-wave producer flags per group

typedef __attribute__((ext_vector_type(8))) short bf16x8;   // MFMA A/B frag (4 VGPRs)
typedef __attribute__((ext_vector_type(4))) short bf16x4;   // 8B LDS store
typedef __attribute__((ext_vector_type(4))) float f32x4;    // MFMA C/D frag

__device__ __forceinline__ unsigned short f2bf_rne(float f) {
    unsigned u = __builtin_bit_cast(unsigned, f);
    unsigned r = u + 0x7fffu + ((u >> 16) & 1u);
    return (unsigned short)(r >> 16);
}
__device__ __forceinline__ float bf2f(unsigned short h) {
    unsigned u = ((unsigned)h) << 16;
    return __builtin_bit_cast(float, u);
}
__device__ __forceinline__ float fast_tanh(float x) {
    x = fminf(15.f, fmaxf(-15.f, x));
    const float e = __expf(2.f * x);
    return (e - 1.f) / (e + 1.f);
}

// ---- Pack W{f,i,c,o}[768][512] into MFMA-B-fragment order, bf16 hi + lo ----
__global__ __launch_bounds__(256) void repack_frag(
    const float* __restrict__ Wf, const float* __restrict__ Wi,
    const float* __restrict__ Wc, const float* __restrict__ Wo,
    unsigned short* __restrict__ Whi, unsigned short* __restrict__ Wlo)
{
    int id = blockIdx.x * 256 + threadIdx.x;           // [0, 1572864)
    int j    = id & 7;
    int lane = (id >> 3) & 63;
    int fkb  = (id >> 9);
    int kb   = fkb % KB_TOT;
    int ng   = fkb / KB_TOT;
    int n = ng * 16 + (lane & 15);
    int k = kb * 32 + (lane >> 4) * 8 + j;
    int g  = n & 3;
    int jh = n >> 2;
    const float* Ws = (g == 0) ? Wf : (g == 1) ? Wi : (g == 2) ? Wc : Wo;
    float w = Ws[k * H_SZ + jh];
    unsigned short wh = f2bf_rne(w);
    unsigned short wl = f2bf_rne(w - bf2f(wh));
    Whi[id] = wh;
    Wlo[id] = wl;
}

__global__ __launch_bounds__(256) void pack_bias(
    const float* __restrict__ bf, const float* __restrict__ bi,
    const float* __restrict__ bc, const float* __restrict__ bo,
    float* __restrict__ bpk, unsigned int* __restrict__ tok)
{
    int c = blockIdx.x * 256 + threadIdx.x;   // [0, 2048)
    if (c < 8 * NFLAG) tok[(size_t)c * 16] = 0u;   // zero flags each replay
    int jh = c >> 2, g = c & 3;
    const float* bs = (g == 0) ? bf : (g == 1) ? bi : (g == 2) ? bc : bo;
    bpk[c] = bs[jh];
}

// ---- Persistent LSTM: all 512 timesteps in one launch ----
// 256 WGs x 256 thr, 1 WG/CU (grid == CU count; co-residency proven R1/R2).
// Weights pinned in AGPR/VGPR via asm keep-alive. 8 sync groups (one per
// 16-row b-tile). Release: per-WAVE flag in its own cacheline after
// wave-local vmcnt(0) of its sc0sc1 h-stores (no WG barrier, no atomics).
// Acquire: every wave polls all 128 group flags in parallel (2 flags/lane),
// then issues its h loads and hides their MALL latency under the x-part
// MFMAs. 3 independent MFMA accumulator chains (hi*Wh, lo*Wh, hi*Wl) cut the
// dependent-MFMA latency 3x. Watchdog: 100ms realtime bail on the spin loop
// (converts any hypothetical sync hang into a visible wrong-answer).
__global__ __launch_bounds__(256, 1) void lstm_persist(
    const float* __restrict__ x_all,           // [T][B][I] fp32
    const unsigned short* __restrict__ Whi,    // frag-packed bf16 hi
    const unsigned short* __restrict__ Wlo,    // frag-packed bf16 lo
    const float* __restrict__ bpk,             // [2048] packed bias
    float* __restrict__ out,                   // [T][B][H] fp32
    unsigned short* __restrict__ hhi,          // [2][B][H] bf16 hi (double buf)
    unsigned short* __restrict__ hlo,          // [2][B][H] bf16 lo
    unsigned int* __restrict__ tok)            // flags: [8 groups][128]*16 uints
{
    __shared__ __align__(16) unsigned short sh_hi[16 * 512];
    __shared__ __align__(16) unsigned short sh_lo[16 * 512];
    __shared__ __align__(16) unsigned short sx_hi[16 * 256];
    __shared__ __align__(16) unsigned short sx_lo[16 * 256];
    __shared__ float preact[16][64];

    const int tid  = threadIdx.x;
    const int lane = tid & 63;
    const int wv   = tid >> 6;
    const int w    = blockIdx.x;
    const int xcd  = w & 7;
    const int q    = w >> 3;
    const int bt   = q & 7;
    const int ngg  = xcd * 4 + (q >> 3);
    const int ng   = ngg * 4 + wv;
    const int b0   = bt * 16;
    const int mrow = lane & 15;
    const int quad = lane >> 4;
    unsigned int* const gflags = tok + (size_t)bt * (NFLAG * 16);
    unsigned int* const myflag = gflags + (size_t)(ngg * 4 + wv) * 16;

    // ---- load weight fragments once; pin (anti-remat keep-alive) ----
    bf16x8 wh[KB_TOT], wl[KB_TOT];
    {
        const bf16x8* __restrict__ Wh8 = (const bf16x8*)Whi;
        const bf16x8* __restrict__ Wl8 = (const bf16x8*)Wlo;
        const int wbase = ng * KB_TOT * 64 + lane;
        #pragma unroll
        for (int kb = 0; kb < KB_TOT; ++kb) {
            wh[kb] = Wh8[wbase + kb * 64];
            wl[kb] = Wl8[wbase + kb * 64];
        }
    }
    #pragma unroll
    for (int kb = 0; kb < KB_TOT; ++kb) {
        asm volatile("" : "+v"(wh[kb]));
        asm volatile("" : "+v"(wl[kb]));
    }

    // ---- pointwise role: thread -> (b_local, hidden_local); C stays in reg ----
    const int bl = tid >> 4;
    const int jl = tid & 15;
    const int pidx = (b0 + bl) * H_SZ + ngg * 16 + jl;
    const f32x4 bias = ((const f32x4*)bpk)[ngg * 16 + jl];
    float Creg = 0.f;

    // ---- staging offsets (short units); XOR swizzle = ((row&15)<<3) shorts ----
    int hgo[4], xgo[4], hlds[4], xlds[4];
    #pragma unroll
    for (int r = 0; r < 4; ++r) {
        const int row = r * 4 + wv;
        hgo[r]  = (b0 + row) * H_SZ + lane * 8;                      // 16B chunk
        hlds[r] = (row * 512 + lane * 8) ^ ((row & 15) << 3);
        xgo[r]  = (b0 + row) * I_SZ + lane * 4;                      // 4 floats
        xlds[r] = (row * 256 + lane * 4) ^ ((row & 15) << 3);
    }
    const int hfr = mrow * 512 + quad * 8;   // A-frag read base (shorts)
    const int xfr = mrow * 256 + quad * 8;
    const int swz = (mrow & 15) << 3;

    // ---- prologue: prefetch x(0) into registers ----
    f32x4 xpre[4];
    #pragma unroll
    for (int r = 0; r < 4; ++r)
        xpre[r] = *(const f32x4*)(x_all + xgo[r]);

    for (int t = 0; t < T_STEPS; ++t) {
        // ---- stage x(t): fp32 regs -> bf16 hi/lo in LDS ----
        #pragma unroll
        for (int r = 0; r < 4; ++r) {
            bf16x4 hv, lv;
            #pragma unroll
            for (int j = 0; j < 4; ++j) {
                const unsigned short hb = f2bf_rne(xpre[r][j]);
                hv[j] = (short)hb;
                lv[j] = (short)f2bf_rne(xpre[r][j] - bf2f(hb));
            }
            *(bf16x4*)&sx_hi[xlds[r]] = hv;
            *(bf16x4*)&sx_lo[xlds[r]] = lv;
        }
        __syncthreads();   // B1: sx ready (also fences preact/sh reuse)

        // ---- acquire + h-load issue (per wave, no WG barrier) ----
        bf16x8 vh[4], vl[4];
        if (t > 0) {
            const unsigned int* f0 = gflags + (size_t)lane * 16;
            const unsigned int* f1 = gflags + (size_t)(lane + 64) * 16;
            const unsigned t0v = (unsigned)t;
            const unsigned long long wd0 = __builtin_amdgcn_s_memrealtime();
            for (;;) {
                unsigned a, b;
                asm volatile("global_load_dword %0, %1, off sc0 sc1"
                             : "=v"(a) : "v"(f0));
                asm volatile("global_load_dword %0, %1, off sc0 sc1"
                             : "=v"(b) : "v"(f1));
                asm volatile("s_waitcnt vmcnt(0)" ::: "memory");
                if (__all((a >= t0v) && (b >= t0v))) break;
                // watchdog: bail after ~100ms (100MHz realtime clock) ->
                // wrong answer instead of dead container if sync ever breaks
                if (__builtin_amdgcn_s_memrealtime() - wd0 > 10000000ull) break;
                __builtin_amdgcn_s_sleep(1);
            }
            __builtin_amdgcn_sched_barrier(0);
            const unsigned short* __restrict__ hhp = hhi + ((t - 1) & 1) * BH;
            const unsigned short* __restrict__ hlp = hlo + ((t - 1) & 1) * BH;
            #pragma unroll
            for (int r = 0; r < 4; ++r) {
                asm volatile("global_load_dwordx4 %0, %1, off sc0 sc1"
                             : "=v"(vh[r]) : "v"(hhp + hgo[r]));
                asm volatile("global_load_dwordx4 %0, %1, off sc0 sc1"
                             : "=v"(vl[r]) : "v"(hlp + hgo[r]));
            }
            __builtin_amdgcn_sched_barrier(0);   // keep x-MFMAs below the issue
        }

        // ---- prefetch x(t+1) (plain cached loads, latency hidden) ----
        if (t + 1 < T_STEPS) {
            const float* __restrict__ xn = x_all + (size_t)(t + 1) * BI;
            #pragma unroll
            for (int r = 0; r < 4; ++r)
                xpre[r] = *(const f32x4*)(xn + xgo[r]);
        }

        // ---- x-part MFMAs: 3 independent chains; hides h-load MALL latency ----
        f32x4 a0 = {0.f, 0.f, 0.f, 0.f};
        f32x4 a1 = {0.f, 0.f, 0.f, 0.f};
        f32x4 a2 = {0.f, 0.f, 0.f, 0.f};
        #pragma unroll
        for (int kxb = 0; kxb < KB_X; ++kxb) {
            const int off = (xfr + kxb * 32) ^ swz;
            const bf16x8 xh = *(const bf16x8*)&sx_hi[off];
            const bf16x8 xl = *(const bf16x8*)&sx_lo[off];
            a0 = __builtin_amdgcn_mfma_f32_16x16x32_bf16(xh, wh[KB_H + kxb], a0, 0, 0, 0);
            a1 = __builtin_amdgcn_mfma_f32_16x16x32_bf16(xl, wh[KB_H + kxb], a1, 0, 0, 0);
            a2 = __builtin_amdgcn_mfma_f32_16x16x32_bf16(xh, wl[KB_H + kxb], a2, 0, 0, 0);
        }

        if (t > 0) {
            asm volatile("s_waitcnt vmcnt(0)" ::: "memory");
            __builtin_amdgcn_sched_barrier(0);
            #pragma unroll
            for (int r = 0; r < 4; ++r) {
                *(bf16x8*)&sh_hi[hlds[r]] = vh[r];
                *(bf16x8*)&sh_lo[hlds[r]] = vl[r];
            }
            __syncthreads();   // B3: sh ready

            // ---- h-part MFMAs ----
            #pragma unroll
            for (int kb = 0; kb < KB_H; ++kb) {
                const int off = (hfr + kb * 32) ^ swz;
                const bf16x8 ah = *(const bf16x8*)&sh_hi[off];
                const bf16x8 al = *(const bf16x8*)&sh_lo[off];
                a0 = __builtin_amdgcn_mfma_f32_16x16x32_bf16(ah, wh[kb], a0, 0, 0, 0);
                a1 = __builtin_amdgcn_mfma_f32_16x16x32_bf16(al, wh[kb], a1, 0, 0, 0);
                a2 = __builtin_amdgcn_mfma_f32_16x16x32_bf16(ah, wl[kb], a2, 0, 0, 0);
            }
        }

        const f32x4 acc = a0 + a1 + a2;

        // ---- stage pre-activations (D: col=lane&15, row=quad*4+r) ----
        #pragma unroll
        for (int r = 0; r < 4; ++r)
            preact[quad * 4 + r][wv * 16 + mrow] = acc[r];
        __syncthreads();   // B4: preact ready

        // ---- pointwise ----
        const f32x4 pa = *(const f32x4*)&preact[bl][jl * 4];
        const float pf = pa[0] + bias[0];
        const float pi = pa[1] + bias[1];
        const float pc = pa[2] + bias[2];
        const float po = pa[3] + bias[3];
        const float fg = 1.f / (1.f + __expf(-pf));
        const float ig = 1.f / (1.f + __expf(-pi));
        const float cb = fast_tanh(pc);
        const float og = 1.f / (1.f + __expf(-po));
        const float Cn = fg * Creg + ig * cb;
        const float hn = og * fast_tanh(Cn);
        Creg = Cn;

        // ---- release: sc0sc1 h-stores -> wave-local drain -> per-wave flag ----
        const int pw = t & 1;
        const unsigned short hb16 = f2bf_rne(hn);
        const unsigned hv32 = hb16;
        const unsigned lv32 = f2bf_rne(hn - bf2f(hb16));
        {
            const unsigned short* ph = hhi + pw * BH + pidx;
            const unsigned short* pl = hlo + pw * BH + pidx;
            asm volatile("global_store_short %0, %1, off sc0 sc1"
                         :: "v"(ph), "v"(hv32) : "memory");
            asm volatile("global_store_short %0, %1, off sc0 sc1"
                         :: "v"(pl), "v"(lv32) : "memory");
            asm volatile("s_waitcnt vmcnt(0)" ::: "memory");
            if (lane == 0) {
                const unsigned fv = (unsigned)(t + 1);
                asm volatile("global_store_dword %0, %1, off sc0 sc1"
                             :: "v"(myflag), "v"(fv) : "memory");
            }
        }
        out[(size_t)t * BH + pidx] = hn;   // off the release critical path
    }
}

extern "C" void kernel_launch(void* const* d_in, const int* in_sizes, int n_in,
                              void* d_out, int out_size, void* d_ws, size_t ws_size,
                              hipStream_t stream)
{
    const float* x  = (const float*)d_in[0];
    const float* Wf = (const float*)d_in[1];
    const float* bf = (const float*)d_in[2];
    const float* Wi = (const float*)d_in[3];
    const float* bi = (const float*)d_in[4];
    const float* Wc = (const float*)d_in[5];
    const float* bc = (const float*)d_in[6];
    const float* Wo = (const float*)d_in[7];
    const float* bo = (const float*)d_in[8];
    float* out = (float*)d_out;

    // ---- workspace layout (all 16B aligned) ----
    unsigned short* Whi = (unsigned short*)d_ws;          // 1,572,864 shorts
    unsigned short* Wlo = Whi + W_ELEMS;                  // 1,572,864 shorts
    float* bpk = (float*)(Wlo + W_ELEMS);                 // 2048 floats
    unsigned short* hb = (unsigned short*)(bpk + NG);
    unsigned short* hhi = hb;                             // [2][65536]
    unsigned short* hlo = hb + 2 * BH;                    // [2][65536]
    unsigned int* tok = (unsigned int*)(hlo + 2 * BH);    // 8*128*16 uints

    repack_frag<<<W_ELEMS / 256, 256, 0, stream>>>(Wf, Wi, Wc, Wo, Whi, Wlo);
    pack_bias<<<NG / 256, 256, 0, stream>>>(bf, bi, bc, bo, bpk, tok);
    lstm_persist<<<NWG, 256, 0, stream>>>(x, Whi, Wlo, bpk, out, hhi, hlo, tok);
}